// Round 10
// baseline (175.198 us; speedup 1.0000x reference)
//
#include <hip/hip_runtime.h>
#include <stdint.h>

typedef _Float16 h2 __attribute__((ext_vector_type(2)));

static constexpr int CDIM = 32;     // channels
static constexpr int NPIX = 16384;  // H*W
static constexpr int SSAM = 1024;   // samples per row
static constexpr int ROWS_PER_BLOCK = 16;

__device__ __forceinline__ uint16_t f2h(float f) {
    union { _Float16 h; uint16_t u; } c;
    c.h = (_Float16)f;
    return c.u;
}

// cross-lane add via DPP quad_perm (VALU-only, no LDS pipe).
template<int CTRL>
__device__ __forceinline__ float dpp_add(float x) {
    int y = __builtin_amdgcn_mov_dpp(__float_as_int(x), CTRL, 0xF, 0xF, true);
    return x + __int_as_float(y);
}

__device__ __forceinline__ float dot2(h2 a, h2 b, float c) {
    return __builtin_amdgcn_fdot2(a, b, c, false);   // v_dot2_f32_f16
}

// ---------------------------------------------------------------------------
// Kernel 0: zero the segbit workspace (capture-safe, no memset dependency).
// ---------------------------------------------------------------------------
__global__ __launch_bounds__(256)
void zero_words(uint32_t* __restrict__ p, int nwords)
{
    int i = blockIdx.x * 256 + threadIdx.x;
    if (i < nwords) p[i] = 0;
}

// ---------------------------------------------------------------------------
// Kernel 1: layout prep.
//   key_feat  [B][C][N] f32 -> key16 [B*N][32] f16 rows (64B, line-aligned)
//   query_feat[B][C][N] f32 -> q16   [B*N][32] f16 rows, PRE-SCALED by C^-0.5
// ---------------------------------------------------------------------------
__global__ __launch_bounds__(256)
void prep_kernel(const float* __restrict__ key_f,
                 const float* __restrict__ query_f,
                 uint8_t* __restrict__ key16,
                 uint8_t* __restrict__ q16,
                 int N, int rows, float scale)
{
    int gI = blockIdx.x * 256 + threadIdx.x;
    if (gI >= rows) return;
    int b = gI / N, n = gI - b * N;
    const size_t cb = (size_t)b * CDIM;

    uint32_t kp[16], qp[16];
#pragma unroll
    for (int c = 0; c < CDIM; c += 2) {
        float k0 = key_f[(cb + c) * N + n];
        float k1 = key_f[(cb + c + 1) * N + n];
        float q0 = query_f[(cb + c) * N + n] * scale;
        float q1 = query_f[(cb + c + 1) * N + n] * scale;
        kp[c >> 1] = (uint32_t)f2h(k0) | ((uint32_t)f2h(k1) << 16);
        qp[c >> 1] = (uint32_t)f2h(q0) | ((uint32_t)f2h(q1) << 16);
    }
    uint4* ko = (uint4*)(key16 + ((size_t)gI << 6));
    uint4* qo = (uint4*)(q16 + ((size_t)gI << 6));
#pragma unroll
    for (int j = 0; j < 4; ++j) {
        ko[j] = make_uint4(kp[4*j], kp[4*j+1], kp[4*j+2], kp[4*j+3]);
        qo[j] = make_uint4(qp[4*j], qp[4*j+1], qp[4*j+2], qp[4*j+3]);
    }
}

// ---------------------------------------------------------------------------
// Kernel 1b: segment bitmap. segbit[b][v][512] u32: bit n set iff seg[b][n]==v.
// A row with segment v answers "is idx a target?" from the 2KB slice [b][v].
// ---------------------------------------------------------------------------
__global__ __launch_bounds__(256)
void segbit_build(const int* __restrict__ seg32,
                  uint32_t* __restrict__ segbit,
                  int N, int rows)
{
    int g = blockIdx.x * 256 + threadIdx.x;
    if (g >= rows) return;
    int b = g / N, n = g - b * N;
    int v = seg32[g] & 63;
    atomicOr(&segbit[(((size_t)(b * 64 + v)) << 9) + (n >> 5)], 1u << (n & 31));
}

// ---------------------------------------------------------------------------
// Kernel 2 (fast): persistent 16-row blocks, ONE barrier per row, 12.4KB LDS
// (wave-capped occupancy: 8 blocks/CU, grid 2048 = exactly one generation).
//  - No row-max (logits bounded ~|8|; exp() f32-safe; identical softmax).
//  - Closed-form KL: kl = -log T - SL/T + log Z (clamp provably inactive).
//  - seg lookups via 2KB bitmap slice, double-buffered + prefetched under
//    the gather shadow (replaces the 16KB seg_lds -> occupancy 2x).
//  - Ping-pong safety: all reads of slot [p] happen before row r's barrier;
//    all writes of slot [p] for row r+2 happen after it. idx is additionally
//    wave-self-contained.
// Fixed geometry: N=16384, S=1024, C=32, 16 rows/block.
// ---------------------------------------------------------------------------
__global__ __launch_bounds__(256)
void affinity_multi(const int* __restrict__ inds,
                    const uint8_t* __restrict__ key16,
                    const uint8_t* __restrict__ q16,
                    const int* __restrict__ seg32,
                    const uint32_t* __restrict__ segbit,
                    float* __restrict__ out,
                    float* __restrict__ ws_kl)
{
    const int tid  = threadIdx.x;
    const int row0 = blockIdx.x * ROWS_PER_BLOCK;
    const int b    = row0 >> 14;           // N = 16384; 16 | N so batch uniform
    const int lane = tid & 63;
    const int w    = tid >> 6;             // wave 0..3
    const int g    = lane >> 2;            // group 0..15
    const int sub  = lane & 3;             // quarter 0..3

    __shared__ __align__(16) int      idx_lds[2][SSAM];  // 2 x 4KB (per-wave)
    __shared__ __align__(16) uint32_t bm_lds[2][512];    // 2 x 2KB bitmap
    __shared__ float red[2][3][4];                       // [parity][Z,T,SL][wave]

    const uint32_t* sbase_bm = segbit + ((size_t)(b * 64) << 9);

    // ---- prologue: stage idx/bitmap/query/seg for row0 ----
    ((int4*)idx_lds[0])[tid] = ((const int4*)(inds + ((size_t)row0 << 10)))[tid];
    int scur = seg32[row0];
    ((uint2*)bm_lds[0])[tid] =
        ((const uint2*)(sbase_bm + ((size_t)(scur & 63) << 9)))[tid];
    uint4 qcur = *(const uint4*)(q16 + ((size_t)row0 << 6) + (sub << 4));
    __syncthreads();   // bm_lds visibility

    const uint8_t* kb = key16 + ((size_t)b << 20);      // b * N * 64 (uniform)
    const uint32_t subs = (uint32_t)(sub << 4);
    const int sbase = (w << 8) + g;                     // sample = sbase + i*16

    for (int r = 0; r < ROWS_PER_BLOCK; ++r) {
        const int row = row0 + r;
        const int p   = r & 1;
        const int* cur = idx_lds[p];
        const bool hasNext = (r + 1 < ROWS_PER_BLOCK);

        // unpack this row's query fragment (loaded last iteration)
        h2 qh0, qh1, qh2, qh3;
        {
            union { uint4 u; h2 h[4]; } qc; qc.u = qcur;
            qh0 = qc.h[0]; qh1 = qc.h[1]; qh2 = qc.h[2]; qh3 = qc.h[3];
        }
        const int seg_n = scur;

        // ---- phase 1: 16 indices from LDS (own wave's range) ----
        int idxs[16];
#pragma unroll
        for (int i = 0; i < 16; ++i)
            idxs[i] = cur[sbase + (i << 4)];

        // ---- phase 2: 16 key gathers (compiler-scheduled) ----
        uint4 kd[16];
#pragma unroll
        for (int i = 0; i < 16; ++i)
            kd[i] = *(const uint4*)(kb + (((uint32_t)idxs[i] << 6) | subs));

        // ---- latency cover: next-row prefetch + bitmap target flags ----
        int4 pre; uint4 qnext; uint2 pre_bm; int snext;
        if (hasNext) {
            pre   = ((const int4*)(inds + ((size_t)(row + 1) << 10)))[tid];
            qnext = *(const uint4*)(q16 + ((size_t)(row + 1) << 6) + (sub << 4));
            snext = seg32[row + 1];
            pre_bm = ((const uint2*)(sbase_bm + ((size_t)(snext & 63) << 9)))[tid];
        }
        int tfm = 0;
#pragma unroll
        for (int j = 0; j < 4; ++j) {
            int idx = cur[sbase + (((j << 2) | sub) << 4)];
            if ((bm_lds[p][idx >> 5] >> (idx & 31)) & 1u) tfm |= 1 << j;
        }

        // ---- phase 3: dots + group reduce ----
        float lgo0 = 0.f, lgo1 = 0.f, lgo2 = 0.f, lgo3 = 0.f;
#pragma unroll
        for (int i = 0; i < 16; ++i) {
            union { uint4 u; h2 h[4]; } kc; kc.u = kd[i];
            float acc = dot2(kc.h[0], qh0, 0.f);
            acc = dot2(kc.h[1], qh1, acc);
            acc = dot2(kc.h[2], qh2, acc);
            acc = dot2(kc.h[3], qh3, acc);
            acc = dpp_add<0xB1>(acc);      // xor 1
            acc = dpp_add<0x4E>(acc);      // xor 2 -> all 4 lanes hold dot
            if (sub == (i & 3)) {          // owner capture (cndmask)
                if ((i >> 2) == 0) lgo0 = acc;
                if ((i >> 2) == 1) lgo1 = acc;
                if ((i >> 2) == 2) lgo2 = acc;
                if ((i >> 2) == 3) lgo3 = acc;
            }
        }

        // ---- owner-lane full-wave logit stores (4 insts, coalesced) ----
        const size_t rowbase = (size_t)row << 10;
        float* op = out + rowbase + (w << 8) + (sub << 4) + g;
        op[0]   = lgo0;
        op[64]  = lgo1;
        op[128] = lgo2;
        op[192] = lgo3;

        // ---- per-lane partials: Z, T, SL; one butterfly for all three ----
        float z  = ((__expf(lgo0) + __expf(lgo1)) + (__expf(lgo2) + __expf(lgo3)));
        float tc = (float)__popc((unsigned)tfm);
        float sl = 0.f;
        sl += (tfm & 1) ? lgo0 : 0.f;
        sl += (tfm & 2) ? lgo1 : 0.f;
        sl += (tfm & 4) ? lgo2 : 0.f;
        sl += (tfm & 8) ? lgo3 : 0.f;
#pragma unroll
        for (int off = 32; off >= 1; off >>= 1) {
            z  += __shfl_xor(z,  off, 64);
            tc += __shfl_xor(tc, off, 64);
            sl += __shfl_xor(sl, off, 64);
        }
        if (lane == 0) {
            red[p][0][w] = z;
            red[p][1][w] = tc;
            red[p][2][w] = sl;
        }

        // ---- commit prefetch into the other parity slots ----
        if (hasNext) {
            ((int4*)idx_lds[p ^ 1])[tid] = pre;
            ((uint2*)bm_lds[p ^ 1])[tid] = pre_bm;
            qcur = qnext;
            scur = snext;
        }
        __syncthreads();                   // THE one barrier per row

        if (tid == 0) {
            if (seg_n != 0) {
                const float Z  = (red[p][0][0] + red[p][0][1]) + (red[p][0][2] + red[p][0][3]);
                const float T  = (red[p][1][0] + red[p][1][1]) + (red[p][1][2] + red[p][1][3]);
                const float SL = (red[p][2][0] + red[p][2][1]) + (red[p][2][2] + red[p][2][3]);
                // T >= 1 always (center sample matches itself)
                ws_kl[row] = -__logf(T) - SL / T + __logf(Z);
            } else {
                ws_kl[row] = 0.f;
            }
        }
    }
}

// ---------------------------------------------------------------------------
// Fallback (generic shapes / tiny ws): per-thread gather from native layout.
// ---------------------------------------------------------------------------
__global__ __launch_bounds__(256)
void affinity_fallback(const float* __restrict__ key_f,
                       const float* __restrict__ query_f,
                       const int*   __restrict__ seg32,
                       const int*   __restrict__ inds,
                       float* __restrict__ out,
                       float* __restrict__ ws_kl,
                       int N, int S, float scale)
{
    const int bid = blockIdx.x;
    const int tid = threadIdx.x;
    const int b   = bid / N;

    __shared__ float q_lds[CDIM];
    __shared__ float redA[4], redB[4], redC[4];

    if (tid < CDIM) {
        int n = bid - b * N;
        q_lds[tid] = query_f[((size_t)(b * CDIM + tid)) * N + n];
    }
    const int seg_n = seg32[bid];
    __syncthreads();

    float q[CDIM];
#pragma unroll
    for (int c = 0; c < CDIM; ++c) q[c] = q_lds[c];

    const size_t rowbase = (size_t)bid * S;
    const int4 iv = ((const int4*)(inds + rowbase))[tid];
    const int idxv[4] = {iv.x, iv.y, iv.z, iv.w};

    float lg[4];
    int   tf[4];
#pragma unroll
    for (int k = 0; k < 4; ++k) {
        int idx = idxv[k];
        tf[k] = (seg32[b * N + idx] == seg_n) ? 1 : 0;
        float acc = 0.f;
#pragma unroll
        for (int c = 0; c < CDIM; ++c)
            acc = fmaf(key_f[((size_t)(b * CDIM + c)) * N + idx], q[c], acc);
        lg[k] = acc * scale;
    }
    ((float4*)(out + rowbase))[tid] = make_float4(lg[0], lg[1], lg[2], lg[3]);

    const int lane = tid & 63, wv = tid >> 6;
    float m = fmaxf(fmaxf(lg[0], lg[1]), fmaxf(lg[2], lg[3]));
#pragma unroll
    for (int off = 32; off >= 1; off >>= 1)
        m = fmaxf(m, __shfl_xor(m, off, 64));
    if (lane == 0) redA[wv] = m;
    __syncthreads();
    m = fmaxf(fmaxf(redA[0], redA[1]), fmaxf(redA[2], redA[3]));

    float e[4], z = 0.f, tcnt = 0.f;
#pragma unroll
    for (int k = 0; k < 4; ++k) {
        e[k] = expf(lg[k] - m);
        z += e[k];
        tcnt += (float)tf[k];
    }
#pragma unroll
    for (int off = 32; off >= 1; off >>= 1) {
        z    += __shfl_xor(z, off, 64);
        tcnt += __shfl_xor(tcnt, off, 64);
    }
    if (lane == 0) { redB[wv] = z; redC[wv] = tcnt; }
    __syncthreads();
    const float Z = redB[0] + redB[1] + redB[2] + redB[3];
    const float T = redC[0] + redC[1] + redC[2] + redC[3];

    float kl = 0.f;
    if (seg_n != 0) {
        const float invZ = 1.f / (Z + 1e-9f);
        const float invT = 1.f / (T + 1e-9f);
        const float nlT  = -logf(T + 1e-9f);
#pragma unroll
        for (int k = 0; k < 4; ++k) {
            if (tf[k]) {
                float p = e[k] * invZ;
                float yp = logf(fmaxf(p, 1e-8f));
                kl += invT * (nlT - yp);
            }
        }
    }
#pragma unroll
    for (int off = 32; off >= 1; off >>= 1)
        kl += __shfl_xor(kl, off, 64);
    if (lane == 0) redA[wv] = kl;
    __syncthreads();
    if (tid == 0)
        ws_kl[bid] = redA[0] + redA[1] + redA[2] + redA[3];
}

// ---------------------------------------------------------------------------
// Kernel 3: deterministic single-block loss reduction (1024 threads).
// ---------------------------------------------------------------------------
__global__ __launch_bounds__(1024)
void loss_reduce(const float* __restrict__ ws_kl,
                 const int* __restrict__ seg32,
                 float* __restrict__ out_loss, int rows)
{
    const int tid = threadIdx.x;
    float s = 0.f, c = 0.f;
    for (int i = tid; i < rows; i += 1024) {
        s += ws_kl[i];
        c += (seg32[i] != 0) ? 1.f : 0.f;
    }
#pragma unroll
    for (int off = 32; off >= 1; off >>= 1) {
        s += __shfl_xor(s, off, 64);
        c += __shfl_xor(c, off, 64);
    }
    __shared__ float sA[16], sB[16];
    const int lane = tid & 63, wv = tid >> 6;
    if (lane == 0) { sA[wv] = s; sB[wv] = c; }
    __syncthreads();
    if (tid == 0) {
        float ts = 0.f, tc = 0.f;
#pragma unroll
        for (int k = 0; k < 16; ++k) { ts += sA[k]; tc += sB[k]; }
        out_loss[0] = ts / (tc + 1e-9f);
    }
}

// ---------------------------------------------------------------------------
extern "C" void kernel_launch(void* const* d_in, const int* in_sizes, int n_in,
                              void* d_out, int out_size, void* d_ws, size_t ws_size,
                              hipStream_t stream)
{
    const float* key_f   = (const float*)d_in[0];
    const float* query_f = (const float*)d_in[1];
    const int*   seg32   = (const int*)d_in[2];
    const int*   inds    = (const int*)d_in[3];
    float* out = (float*)d_out;

    const int N    = NPIX;
    const int rows = in_sizes[2];            // B*N
    const int S    = in_sizes[3] / rows;     // 1024
    const float scale = (float)(1.0 / sqrt((double)CDIM));
    const int B    = rows / N;

    // ws layout: key16 rows | q16 rows | segbit (B*64*2KB) | kl array
    const size_t off_q16 = (size_t)rows * 64;
    const size_t off_sb  = off_q16 + (size_t)rows * 64;
    const size_t sb_words = (size_t)B * 64 * 512;
    const size_t off_kl  = (off_sb + sb_words * 4 + 255) & ~(size_t)255;
    const size_t need    = off_kl + (size_t)rows * 4;

    uint8_t* wsb = (uint8_t*)d_ws;
    const bool geom_ok = (S == SSAM) && (rows % N == 0) &&
                         (rows % ROWS_PER_BLOCK == 0);

    if (ws_size >= need && geom_ok) {
        uint8_t*  key16  = wsb;
        uint8_t*  q16    = wsb + off_q16;
        uint32_t* segbit = (uint32_t*)(wsb + off_sb);
        float*    wskl   = (float*)(wsb + off_kl);

        zero_words<<<(int)((sb_words + 255) / 256), 256, 0, stream>>>(
            segbit, (int)sb_words);
        prep_kernel<<<(rows + 255) / 256, 256, 0, stream>>>(
            key_f, query_f, key16, q16, N, rows, scale);
        segbit_build<<<(rows + 255) / 256, 256, 0, stream>>>(
            seg32, segbit, N, rows);
        affinity_multi<<<rows / ROWS_PER_BLOCK, 256, 0, stream>>>(
            inds, key16, q16, seg32, segbit, out, wskl);
        loss_reduce<<<1, 1024, 0, stream>>>(wskl, seg32, out + (size_t)rows * S, rows);
    } else {
        float* wskl = (float*)d_ws;
        affinity_fallback<<<rows, 256, 0, stream>>>(
            key_f, query_f, seg32, inds, out, wskl, N, S, scale);
        loss_reduce<<<1, 1024, 0, stream>>>(wskl, seg32, out + (size_t)rows * S, rows);
    }
}